// Round 1
// baseline (146.460 us; speedup 1.0000x reference)
//
#include <hip/hip_runtime.h>

// Problem constants (from setup_inputs): N=4096, C=64, A=256
#define N_ROWS 4096
#define C_CLS  64
#define A_DIM  256
#define BK     32           // K-chunk (over b) per block in phase 1
#define KCHUNK (A_DIM / BK) // 8
#define GRID   (C_CLS * KCHUNK)  // 512 blocks: (y, kc) pairs; also 8 rows/block in phase 2

// ---------------------------------------------------------------------------
// Module-global device storage (NOT the harness workspace, which is poisoned
// with a 256 MiB fill every iteration). All of these are written before being
// read within each launch, except the two counters which are monotonic:
// every launch adds exactly GRID to each, so they stay ≡ 0 (mod GRID) at
// launch start — the barrier target is computed by rounding the ticket up to
// the next multiple of GRID, needing no reset (graph-replay / rocprof-replay
// safe).
// ---------------------------------------------------------------------------
__device__ float    g_Spart[KCHUNK * C_CLS * C_CLS]; // 128 KB partial quad-forms
__device__ float    g_part[GRID];                    // per-block loss partials
__device__ unsigned g_bar  = 0;                      // monotonic grid barrier
__device__ unsigned g_tick = 0;                      // monotonic finalize ticket

// ---------------------------------------------------------------------------
// ONE kernel, three phases:
//  1) Spart[kc][y][c] = partial over b-chunk of (w_c-w_y)^T CV[y] (w_c-w_y)
//  2) grid barrier, then per-row softmax CE on pred + 0.5*Lambda*sum_k Spart
//  3) ticket: last block deterministically reduces 512 partials -> mean loss
// Residency: 48 KB LDS -> 3 blocks/CU capacity; __launch_bounds__(256,2)
// guarantees >=2 blocks/CU by register cap -> 512 <= 2*256 blocks co-resident,
// so the spin barrier cannot deadlock.
// ---------------------------------------------------------------------------
__global__ __launch_bounds__(256, 2) void fused_kernel(
    const float* __restrict__ W,       // [C][A]
    const float* __restrict__ CV,      // [C][A][A]
    const float* __restrict__ pred,    // [N][C]
    const int*   __restrict__ labels,  // [N]
    const float* __restrict__ lambda_p,
    float* __restrict__ out)
{
    __shared__ float Vt[BK][A_DIM];   // 32 KB : Vt[k][a] = CV[y][kb+k][a]
    __shared__ float Dt[BK][C_CLS];   //  8 KB : Dt[k][c] = W[c][kb+k]-W[y][kb+k]
    __shared__ float Psum[32][C_CLS]; //  8 KB : per-(a-group) partial S
    __shared__ float wsum4[4];
    __shared__ int   s_last;

    const int t = threadIdx.x;

    // ======================= phase 1: quad-form partials ====================
    {
        const int y  = blockIdx.x >> 3;          // blockIdx / KCHUNK
        const int kc = blockIdx.x & 7;           // k-chunk index
        const int kb = kc * BK;                  // b-range start

        // ---- stage Vt: rows kb..kb+BK-1 of CV[y] (contiguous 32 KB) ----
        {
            const float4* src = (const float4*)(CV + ((size_t)y * A_DIM * A_DIM
                                                      + (size_t)kb * A_DIM));
            float4* vdst = (float4*)&Vt[0][0];
            #pragma unroll
            for (int i = 0; i < (BK * A_DIM / 4) / 256; ++i)
                vdst[t + i * 256] = src[t + i * 256];
        }

        // ---- stage Dt (transposed diff chunk) ----
        {
            const int kq    = (t & 7) * 4;   // k = kq..kq+3
            const int chalf = t >> 3;        // 0..31
            const float4 wy = *(const float4*)(W + y * A_DIM + kb + kq);
            #pragma unroll
            for (int cc = 0; cc < 2; ++cc) {
                const int c = chalf + cc * 32;
                const float4 wc = *(const float4*)(W + c * A_DIM + kb + kq);
                Dt[kq + 0][c] = wc.x - wy.x;
                Dt[kq + 1][c] = wc.y - wy.y;
                Dt[kq + 2][c] = wc.z - wy.z;
                Dt[kq + 3][c] = wc.w - wy.w;
            }
        }
        __syncthreads();

        // ---- 8x8 register tile: c0=(t%8)*8 covers 64 c, a0=(t/8)*8 covers 256 a
        const int c0 = (t & 7) * 8;
        const int a0 = (t >> 3) * 8;
        float acc[8][8];
        #pragma unroll
        for (int i = 0; i < 8; ++i)
            #pragma unroll
            for (int j = 0; j < 8; ++j) acc[i][j] = 0.0f;

        #pragma unroll 2
        for (int k = 0; k < BK; ++k) {
            const float4 a_lo = *(const float4*)&Vt[k][a0];
            const float4 a_hi = *(const float4*)&Vt[k][a0 + 4];
            const float4 d_lo = *(const float4*)&Dt[k][c0];
            const float4 d_hi = *(const float4*)&Dt[k][c0 + 4];
            const float af[8] = {a_lo.x, a_lo.y, a_lo.z, a_lo.w,
                                 a_hi.x, a_hi.y, a_hi.z, a_hi.w};
            const float df[8] = {d_lo.x, d_lo.y, d_lo.z, d_lo.w,
                                 d_hi.x, d_hi.y, d_hi.z, d_hi.w};
            #pragma unroll
            for (int i = 0; i < 8; ++i)
                #pragma unroll
                for (int j = 0; j < 8; ++j)
                    acc[i][j] += df[i] * af[j];
        }

        // ---- fused epilogue: s_i = sum_j acc[i][j] * (W[c0+i][a0+j]-W[y][a0+j])
        float s[8];
        {
            const float4 wy_lo = *(const float4*)(W + y * A_DIM + a0);
            const float4 wy_hi = *(const float4*)(W + y * A_DIM + a0 + 4);
            const float wyv[8] = {wy_lo.x, wy_lo.y, wy_lo.z, wy_lo.w,
                                  wy_hi.x, wy_hi.y, wy_hi.z, wy_hi.w};
            #pragma unroll
            for (int i = 0; i < 8; ++i) {
                const int c = c0 + i;
                const float4 wc_lo = *(const float4*)(W + c * A_DIM + a0);
                const float4 wc_hi = *(const float4*)(W + c * A_DIM + a0 + 4);
                const float wcv[8] = {wc_lo.x, wc_lo.y, wc_lo.z, wc_lo.w,
                                      wc_hi.x, wc_hi.y, wc_hi.z, wc_hi.w};
                float ss = 0.0f;
                #pragma unroll
                for (int j = 0; j < 8; ++j)
                    ss += acc[i][j] * (wcv[j] - wyv[j]);
                s[i] = ss;
            }
        }
        const int ag = t >> 3;   // a-group 0..31
        *(float4*)&Psum[ag][c0]     = make_float4(s[0], s[1], s[2], s[3]);
        *(float4*)&Psum[ag][c0 + 4] = make_float4(s[4], s[5], s[6], s[7]);
        __syncthreads();

        if (t < C_CLS) {
            float r = 0.0f;
            #pragma unroll
            for (int g = 0; g < 32; ++g) r += Psum[g][t];
            g_Spart[(size_t)kc * C_CLS * C_CLS + y * C_CLS + t] = r;
        }
    }

    // ========================== grid barrier ================================
    // Release: each wave's stores reached L2 before s_barrier (waitcnt);
    // thread 0's device-scope fence + agent RMW flushes the XCD L2 to the
    // coherence point. Acquire: post-spin fence invalidates stale L1/L2 lines
    // (incl. previous-iteration copies of g_Spart) before phase-2 reads.
    __syncthreads();
    if (t == 0) {
        __threadfence();
        unsigned v = __hip_atomic_fetch_add(&g_bar, 1u, __ATOMIC_ACQ_REL,
                                            __HIP_MEMORY_SCOPE_AGENT) + 1u;
        const unsigned target = (v + (GRID - 1u)) & ~(unsigned)(GRID - 1u);
        while (__hip_atomic_load(&g_bar, __ATOMIC_RELAXED,
                                 __HIP_MEMORY_SCOPE_AGENT) < target)
            __builtin_amdgcn_s_sleep(4);
        __threadfence();
    }
    __syncthreads();

    // ================= phase 2: softmax CE, 2 rows per wave =================
    {
        const int lane = t & 63;
        const int wv   = t >> 6;
        const int gw   = (int)blockIdx.x * 4 + wv;     // 0..2047
        const float lam = 0.5f * lambda_p[0];

        float acc_nll = 0.0f;
        #pragma unroll
        for (int r = 0; r < 2; ++r) {
            const int n = r * 2048 + gw;
            const int y = labels[n];
            float sp = 0.0f;
            #pragma unroll
            for (int k = 0; k < KCHUNK; ++k)
                sp += g_Spart[k * C_CLS * C_CLS + y * C_CLS + lane];
            const float logit = pred[n * C_CLS + lane] + lam * sp;

            float m = logit;
            #pragma unroll
            for (int off = 32; off > 0; off >>= 1)
                m = fmaxf(m, __shfl_xor(m, off, 64));
            float e = __expf(logit - m);
            float ssum = e;
            #pragma unroll
            for (int off = 32; off > 0; off >>= 1)
                ssum += __shfl_xor(ssum, off, 64);
            const float ly = __shfl(logit, y, 64);
            acc_nll += logf(ssum) + m - ly;
        }

        if (lane == 0) wsum4[wv] = acc_nll;
        __syncthreads();
        if (t == 0) {
            g_part[blockIdx.x] = wsum4[0] + wsum4[1] + wsum4[2] + wsum4[3];
            __threadfence();   // release g_part before taking the ticket
            unsigned v = __hip_atomic_fetch_add(&g_tick, 1u, __ATOMIC_ACQ_REL,
                                                __HIP_MEMORY_SCOPE_AGENT) + 1u;
            s_last = ((v & (GRID - 1u)) == 0u) ? 1 : 0;
        }
        __syncthreads();

        // ============ phase 3: last block reduces deterministically =========
        if (s_last) {
            float v = __hip_atomic_load(&g_part[t], __ATOMIC_RELAXED,
                                        __HIP_MEMORY_SCOPE_AGENT)
                    + __hip_atomic_load(&g_part[t + 256], __ATOMIC_RELAXED,
                                        __HIP_MEMORY_SCOPE_AGENT);
            #pragma unroll
            for (int off = 32; off > 0; off >>= 1)
                v += __shfl_xor(v, off, 64);
            if (lane == 0) wsum4[wv] = v;
            __syncthreads();
            if (t == 0)
                out[0] = (wsum4[0] + wsum4[1] + wsum4[2] + wsum4[3])
                         * (1.0f / (float)N_ROWS);
        }
    }
}

// ---------------------------------------------------------------------------
extern "C" void kernel_launch(void* const* d_in, const int* in_sizes, int n_in,
                              void* d_out, int out_size, void* d_ws, size_t ws_size,
                              hipStream_t stream) {
    (void)in_sizes; (void)n_in; (void)out_size; (void)d_ws; (void)ws_size;
    const float* W      = (const float*)d_in[0];   // fc_weight [64][256]
    // d_in[1] = features (unused by the reference computation)
    const float* pred   = (const float*)d_in[2];   // [4096][64]
    const int*   labels = (const int*)d_in[3];     // [4096]
    const float* lam    = (const float*)d_in[4];   // scalar
    const float* CV     = (const float*)d_in[5];   // [64][256][256]
    float* out = (float*)d_out;

    fused_kernel<<<dim3(GRID), dim3(256), 0, stream>>>(W, CV, pred, labels, lam, out);
}

// Round 2
// 105.321 us; speedup vs baseline: 1.3906x; 1.3906x over previous
//
#include <hip/hip_runtime.h>

// Problem constants (from setup_inputs): N=4096, C=64, A=256
#define N_ROWS 4096
#define C_CLS  64
#define A_DIM  256
#define BK     32           // K-chunk (over b) per block in phase 1
#define KCHUNK (A_DIM / BK) // 8
#define GRID   (C_CLS * KCHUNK)  // 512 blocks: (y, kc) pairs; also 8 rows/block in phase 2

// ---------------------------------------------------------------------------
// Module-global device storage (NOT the harness workspace, which gets a
// 256 MiB poison-fill every iteration). Cross-block communication uses ONLY
// relaxed agent-scope atomics (sc1-flagged ops, coherent at the LLC, no
// per-XCD L2 involvement) — round 1 measured ~75 us for a fence/ACQ_REL
// barrier because every ordered agent op emits a full L2 writeback or
// invalidate sweep (buffer_wbl2/buffer_inv sc1) per block. Relaxed atomics
// emit no sweeps; ordering store->signal comes from the vmcnt(0) drain that
// __syncthreads already performs (store completion at the coherence point).
// The two counters are monotonic: each launch adds exactly GRID, so no reset
// is needed (graph-replay / rocprof-replay safe).
// ---------------------------------------------------------------------------
__device__ float    g_Spart[KCHUNK * C_CLS * C_CLS]; // 128 KB partial quad-forms
__device__ float    g_part[GRID];                    // per-block loss partials
__device__ unsigned g_bar  = 0;                      // monotonic grid barrier
__device__ unsigned g_tick = 0;                      // monotonic finalize ticket

// ---------------------------------------------------------------------------
// ONE kernel, three phases:
//  1) Spart[kc][y][c] = partial over b-chunk of (w_c-w_y)^T CV[y] (w_c-w_y)
//  2) sweep-free grid barrier, then per-row softmax CE on
//     pred + 0.5*Lambda*sum_k Spart
//  3) ticket: last block deterministically reduces 512 partials -> mean loss
// Residency: __launch_bounds__(256,2) + 48.5 KB LDS guarantee 2 blocks/CU ->
// all 512 blocks co-resident on 256 CUs, so the spin barrier cannot deadlock.
// ---------------------------------------------------------------------------
__global__ __launch_bounds__(256, 2) void fused_kernel(
    const float* __restrict__ W,       // [C][A]
    const float* __restrict__ CV,      // [C][A][A]
    const float* __restrict__ pred,    // [N][C]
    const int*   __restrict__ labels,  // [N]
    const float* __restrict__ lambda_p,
    float* __restrict__ out)
{
    __shared__ float Vt[BK][A_DIM];   // 32 KB : Vt[k][a] = CV[y][kb+k][a]
    __shared__ float Dt[BK][C_CLS];   //  8 KB : Dt[k][c] = W[c][kb+k]-W[y][kb+k]
    __shared__ float Psum[32][C_CLS]; //  8 KB : per-(a-group) partial S
    __shared__ float wsum4[4];
    __shared__ int   s_last;

    const int t = threadIdx.x;

    // ======================= phase 1: quad-form partials ====================
    {
        const int y  = blockIdx.x >> 3;          // blockIdx / KCHUNK
        const int kc = blockIdx.x & 7;           // k-chunk index
        const int kb = kc * BK;                  // b-range start

        // ---- stage Vt: rows kb..kb+BK-1 of CV[y] (contiguous 32 KB) ----
        {
            const float4* src = (const float4*)(CV + ((size_t)y * A_DIM * A_DIM
                                                      + (size_t)kb * A_DIM));
            float4* vdst = (float4*)&Vt[0][0];
            #pragma unroll
            for (int i = 0; i < (BK * A_DIM / 4) / 256; ++i)
                vdst[t + i * 256] = src[t + i * 256];
        }

        // ---- stage Dt (transposed diff chunk) ----
        {
            const int kq    = (t & 7) * 4;   // k = kq..kq+3
            const int chalf = t >> 3;        // 0..31
            const float4 wy = *(const float4*)(W + y * A_DIM + kb + kq);
            #pragma unroll
            for (int cc = 0; cc < 2; ++cc) {
                const int c = chalf + cc * 32;
                const float4 wc = *(const float4*)(W + c * A_DIM + kb + kq);
                Dt[kq + 0][c] = wc.x - wy.x;
                Dt[kq + 1][c] = wc.y - wy.y;
                Dt[kq + 2][c] = wc.z - wy.z;
                Dt[kq + 3][c] = wc.w - wy.w;
            }
        }
        __syncthreads();

        // ---- 8x8 register tile: c0=(t%8)*8 covers 64 c, a0=(t/8)*8 covers 256 a
        const int c0 = (t & 7) * 8;
        const int a0 = (t >> 3) * 8;
        float acc[8][8];
        #pragma unroll
        for (int i = 0; i < 8; ++i)
            #pragma unroll
            for (int j = 0; j < 8; ++j) acc[i][j] = 0.0f;

        #pragma unroll 2
        for (int k = 0; k < BK; ++k) {
            const float4 a_lo = *(const float4*)&Vt[k][a0];
            const float4 a_hi = *(const float4*)&Vt[k][a0 + 4];
            const float4 d_lo = *(const float4*)&Dt[k][c0];
            const float4 d_hi = *(const float4*)&Dt[k][c0 + 4];
            const float af[8] = {a_lo.x, a_lo.y, a_lo.z, a_lo.w,
                                 a_hi.x, a_hi.y, a_hi.z, a_hi.w};
            const float df[8] = {d_lo.x, d_lo.y, d_lo.z, d_lo.w,
                                 d_hi.x, d_hi.y, d_hi.z, d_hi.w};
            #pragma unroll
            for (int i = 0; i < 8; ++i)
                #pragma unroll
                for (int j = 0; j < 8; ++j)
                    acc[i][j] += df[i] * af[j];
        }

        // ---- fused epilogue: s_i = sum_j acc[i][j] * (W[c0+i][a0+j]-W[y][a0+j])
        float s[8];
        {
            const float4 wy_lo = *(const float4*)(W + y * A_DIM + a0);
            const float4 wy_hi = *(const float4*)(W + y * A_DIM + a0 + 4);
            const float wyv[8] = {wy_lo.x, wy_lo.y, wy_lo.z, wy_lo.w,
                                  wy_hi.x, wy_hi.y, wy_hi.z, wy_hi.w};
            #pragma unroll
            for (int i = 0; i < 8; ++i) {
                const int c = c0 + i;
                const float4 wc_lo = *(const float4*)(W + c * A_DIM + a0);
                const float4 wc_hi = *(const float4*)(W + c * A_DIM + a0 + 4);
                const float wcv[8] = {wc_lo.x, wc_lo.y, wc_lo.z, wc_lo.w,
                                      wc_hi.x, wc_hi.y, wc_hi.z, wc_hi.w};
                float ss = 0.0f;
                #pragma unroll
                for (int j = 0; j < 8; ++j)
                    ss += acc[i][j] * (wcv[j] - wyv[j]);
                s[i] = ss;
            }
        }
        const int ag = t >> 3;   // a-group 0..31
        *(float4*)&Psum[ag][c0]     = make_float4(s[0], s[1], s[2], s[3]);
        *(float4*)&Psum[ag][c0 + 4] = make_float4(s[4], s[5], s[6], s[7]);
        __syncthreads();

        if (t < C_CLS) {
            float r = 0.0f;
            #pragma unroll
            for (int g = 0; g < 32; ++g) r += Psum[g][t];
            // sc1 store: lands at the LLC (agent coherence point), no sweep
            __hip_atomic_store(&g_Spart[kc * C_CLS * C_CLS + y * C_CLS + t], r,
                               __ATOMIC_RELAXED, __HIP_MEMORY_SCOPE_AGENT);
        }
    }

    // ============== grid barrier — sweep-free, relaxed atomics ==============
    // __syncthreads drains vmcnt(0): all this block's sc1 Spart stores have
    // reached the LLC before thread 0 signals. Readers use sc1 loads (bypass
    // the possibly-stale per-XCD L2), so no acquire/release sweeps are needed.
    __syncthreads();
    if (t == 0) {
        unsigned v = __hip_atomic_fetch_add(&g_bar, 1u, __ATOMIC_RELAXED,
                                            __HIP_MEMORY_SCOPE_AGENT) + 1u;
        const unsigned target = (v + (GRID - 1u)) & ~(unsigned)(GRID - 1u);
        while (__hip_atomic_load(&g_bar, __ATOMIC_RELAXED,
                                 __HIP_MEMORY_SCOPE_AGENT) < target)
            __builtin_amdgcn_s_sleep(64);   // ~4K cycle backoff: keep the LLC line cool
        asm volatile("" ::: "memory");      // compiler fence: no hoisting loads above spin
    }
    __syncthreads();

    // ================= phase 2: softmax CE, 2 rows per wave =================
    {
        const int lane = t & 63;
        const int wv   = t >> 6;
        const int gw   = (int)blockIdx.x * 4 + wv;     // 0..2047
        const float lam = 0.5f * lambda_p[0];

        float acc_nll = 0.0f;
        #pragma unroll
        for (int r = 0; r < 2; ++r) {
            const int n = r * 2048 + gw;
            const int y = labels[n];
            float sp = 0.0f;
            #pragma unroll
            for (int k = 0; k < KCHUNK; ++k)
                sp += __hip_atomic_load(&g_Spart[k * C_CLS * C_CLS + y * C_CLS + lane],
                                        __ATOMIC_RELAXED, __HIP_MEMORY_SCOPE_AGENT);
            const float logit = pred[n * C_CLS + lane] + lam * sp;

            float m = logit;
            #pragma unroll
            for (int off = 32; off > 0; off >>= 1)
                m = fmaxf(m, __shfl_xor(m, off, 64));
            float e = __expf(logit - m);
            float ssum = e;
            #pragma unroll
            for (int off = 32; off > 0; off >>= 1)
                ssum += __shfl_xor(ssum, off, 64);
            const float ly = __shfl(logit, y, 64);
            acc_nll += logf(ssum) + m - ly;
        }

        if (lane == 0) wsum4[wv] = acc_nll;
        __syncthreads();
        if (t == 0) {
            __hip_atomic_store(&g_part[blockIdx.x],
                               wsum4[0] + wsum4[1] + wsum4[2] + wsum4[3],
                               __ATOMIC_RELAXED, __HIP_MEMORY_SCOPE_AGENT);
            // order my g_part store (at LLC) before my ticket RMW — plain
            // vmcnt drain, no cache sweep
            asm volatile("s_waitcnt vmcnt(0)" ::: "memory");
            unsigned v = __hip_atomic_fetch_add(&g_tick, 1u, __ATOMIC_RELAXED,
                                                __HIP_MEMORY_SCOPE_AGENT) + 1u;
            s_last = ((v & (GRID - 1u)) == 0u) ? 1 : 0;
        }
        __syncthreads();

        // ============ phase 3: last block reduces deterministically =========
        if (s_last) {
            float v = __hip_atomic_load(&g_part[t], __ATOMIC_RELAXED,
                                        __HIP_MEMORY_SCOPE_AGENT)
                    + __hip_atomic_load(&g_part[t + 256], __ATOMIC_RELAXED,
                                        __HIP_MEMORY_SCOPE_AGENT);
            #pragma unroll
            for (int off = 32; off > 0; off >>= 1)
                v += __shfl_xor(v, off, 64);
            if (lane == 0) wsum4[wv] = v;
            __syncthreads();
            if (t == 0)
                out[0] = (wsum4[0] + wsum4[1] + wsum4[2] + wsum4[3])
                         * (1.0f / (float)N_ROWS);
        }
    }
}

// ---------------------------------------------------------------------------
extern "C" void kernel_launch(void* const* d_in, const int* in_sizes, int n_in,
                              void* d_out, int out_size, void* d_ws, size_t ws_size,
                              hipStream_t stream) {
    (void)in_sizes; (void)n_in; (void)out_size; (void)d_ws; (void)ws_size;
    const float* W      = (const float*)d_in[0];   // fc_weight [64][256]
    // d_in[1] = features (unused by the reference computation)
    const float* pred   = (const float*)d_in[2];   // [4096][64]
    const int*   labels = (const int*)d_in[3];     // [4096]
    const float* lam    = (const float*)d_in[4];   // scalar
    const float* CV     = (const float*)d_in[5];   // [64][256][256]
    float* out = (float*)d_out;

    fused_kernel<<<dim3(GRID), dim3(256), 0, stream>>>(W, CV, pred, labels, lam, out);
}

// Round 3
// 91.404 us; speedup vs baseline: 1.6023x; 1.1523x over previous
//
#include <hip/hip_runtime.h>

// Problem constants (from setup_inputs): N=4096, C=64, A=256
#define N_ROWS 4096
#define C_CLS  64
#define A_DIM  256
#define BK     32           // K-chunk (over b) per block in kernel A
#define KCHUNK (A_DIM / BK) // 8
#define LOSS_BLOCKS 256     // kernel B blocks (4 waves each, 4 rows/wave)

// ---------------------------------------------------------------------------
// Module-global storage (NOT the harness workspace — that gets a 256 MiB
// poison fill every iteration). Spart/g_part are written before read every
// launch. g_tick is monotonic: each launch adds exactly LOSS_BLOCKS, so it
// stays ≡ 0 (mod LOSS_BLOCKS) at launch start — the "am I last" test needs
// no reset (graph-replay / rocprof-replay safe; validated rounds 1-2).
//
// Lesson from rounds 1-2: an in-kernel grid barrier costs ~30-75 us on this
// chip (ordered agent atomics sweep per-XCD L2s; even relaxed spin barriers
// carry ~30 us of unexplained cost). Kernel boundaries cost ~2-4 us. So:
// two kernels, boundary-synced; the only cross-block protocol is the tiny
// one-RMW-per-block finalize ticket inside kernel B.
// ---------------------------------------------------------------------------
__device__ float    g_Spart[KCHUNK * C_CLS * C_CLS]; // 128 KB partial quad-forms
__device__ float    g_part[LOSS_BLOCKS];             // per-block loss partials
__device__ unsigned g_tick = 0;                      // monotonic finalize ticket

// ---------------------------------------------------------------------------
// Kernel A: Spart[kc][y][c] = partial over b-chunk of (w_c-w_y)^T CV[y] (w_c-w_y)
// grid = 64*KCHUNK = 512 blocks (2 blocks/CU). Proven structure (round 0).
// ---------------------------------------------------------------------------
__global__ __launch_bounds__(256) void qform_kernel(
    const float* __restrict__ W,      // [C][A]
    const float* __restrict__ CV)     // [C][A][A]
{
    __shared__ float Vt[BK][A_DIM];   // 32 KB : Vt[k][a] = CV[y][kb+k][a]
    __shared__ float Dt[BK][C_CLS];   //  8 KB : Dt[k][c] = W[c][kb+k]-W[y][kb+k]
    __shared__ float Psum[32][C_CLS]; //  8 KB : per-(a-group) partial S

    const int t  = threadIdx.x;
    const int y  = blockIdx.x >> 3;          // blockIdx / KCHUNK
    const int kc = blockIdx.x & 7;           // k-chunk index
    const int kb = kc * BK;                  // b-range start

    // ---- stage Vt: rows kb..kb+BK-1 of CV[y] (contiguous 32 KB, coalesced) ----
    {
        const float4* src = (const float4*)(CV + ((size_t)y * A_DIM * A_DIM
                                                  + (size_t)kb * A_DIM));
        float4* vdst = (float4*)&Vt[0][0];
        #pragma unroll
        for (int i = 0; i < (BK * A_DIM / 4) / 256; ++i)
            vdst[t + i * 256] = src[t + i * 256];
    }

    // ---- stage Dt (transposed diff chunk) ----
    {
        const int kq    = (t & 7) * 4;   // k = kq..kq+3
        const int chalf = t >> 3;        // 0..31
        const float4 wy = *(const float4*)(W + y * A_DIM + kb + kq);
        #pragma unroll
        for (int cc = 0; cc < 2; ++cc) {
            const int c = chalf + cc * 32;
            const float4 wc = *(const float4*)(W + c * A_DIM + kb + kq);
            Dt[kq + 0][c] = wc.x - wy.x;
            Dt[kq + 1][c] = wc.y - wy.y;
            Dt[kq + 2][c] = wc.z - wy.z;
            Dt[kq + 3][c] = wc.w - wy.w;
        }
    }
    __syncthreads();

    // ---- 8x8 register tile: c0=(t%8)*8 covers 64 c, a0=(t/8)*8 covers 256 a ----
    const int c0 = (t & 7) * 8;
    const int a0 = (t >> 3) * 8;
    float acc[8][8];
    #pragma unroll
    for (int i = 0; i < 8; ++i)
        #pragma unroll
        for (int j = 0; j < 8; ++j) acc[i][j] = 0.0f;

    #pragma unroll 2
    for (int k = 0; k < BK; ++k) {
        const float4 a_lo = *(const float4*)&Vt[k][a0];
        const float4 a_hi = *(const float4*)&Vt[k][a0 + 4];
        const float4 d_lo = *(const float4*)&Dt[k][c0];
        const float4 d_hi = *(const float4*)&Dt[k][c0 + 4];
        const float af[8] = {a_lo.x, a_lo.y, a_lo.z, a_lo.w,
                             a_hi.x, a_hi.y, a_hi.z, a_hi.w};
        const float df[8] = {d_lo.x, d_lo.y, d_lo.z, d_lo.w,
                             d_hi.x, d_hi.y, d_hi.z, d_hi.w};
        #pragma unroll
        for (int i = 0; i < 8; ++i)
            #pragma unroll
            for (int j = 0; j < 8; ++j)
                acc[i][j] += df[i] * af[j];
    }

    // ---- fused epilogue: s_i = sum_j acc[i][j] * (W[c0+i][a0+j] - W[y][a0+j]) ----
    float s[8];
    {
        const float4 wy_lo = *(const float4*)(W + y * A_DIM + a0);
        const float4 wy_hi = *(const float4*)(W + y * A_DIM + a0 + 4);
        const float wyv[8] = {wy_lo.x, wy_lo.y, wy_lo.z, wy_lo.w,
                              wy_hi.x, wy_hi.y, wy_hi.z, wy_hi.w};
        #pragma unroll
        for (int i = 0; i < 8; ++i) {
            const int c = c0 + i;
            const float4 wc_lo = *(const float4*)(W + c * A_DIM + a0);
            const float4 wc_hi = *(const float4*)(W + c * A_DIM + a0 + 4);
            const float wcv[8] = {wc_lo.x, wc_lo.y, wc_lo.z, wc_lo.w,
                                  wc_hi.x, wc_hi.y, wc_hi.z, wc_hi.w};
            float ss = 0.0f;
            #pragma unroll
            for (int j = 0; j < 8; ++j)
                ss += acc[i][j] * (wcv[j] - wyv[j]);
            s[i] = ss;
        }
    }
    // conflict-free staging: 8 consecutive floats per thread (2x ds_write_b128)
    const int ag = t >> 3;   // a-group 0..31
    *(float4*)&Psum[ag][c0]     = make_float4(s[0], s[1], s[2], s[3]);
    *(float4*)&Psum[ag][c0 + 4] = make_float4(s[4], s[5], s[6], s[7]);
    __syncthreads();

    if (t < C_CLS) {
        float r = 0.0f;
        #pragma unroll
        for (int g = 0; g < 32; ++g) r += Psum[g][t];   // stride-1 across lanes
        g_Spart[kc * C_CLS * C_CLS + y * C_CLS + t] = r;
    }
}

// ---------------------------------------------------------------------------
// Kernel B: per-row softmax CE on aug = pred + 0.5*Lambda*sum_k Spart[k][y],
// one wave per row-group (4 rows), all loads hoisted into flight before the
// math; then ticket-based finalize (last block reduces 256 partials in the
// SAME deterministic order as the round-0 finalize kernel -> absmax 0).
// ---------------------------------------------------------------------------
__global__ __launch_bounds__(256) void loss_kernel(
    const float* __restrict__ pred,    // [N][C]
    const int*   __restrict__ labels,  // [N]
    const float* __restrict__ lambda_p,
    float* __restrict__ out)
{
    __shared__ float wsum[4];
    __shared__ int   s_last;

    const int t    = threadIdx.x;
    const int lane = t & 63;
    const int wv   = t >> 6;
    const int gw   = (int)blockIdx.x * 4 + wv;   // global wave id, 0..1023
    const float lam = 0.5f * lambda_p[0];

    // ---- hoist all loads: 4 labels -> 4 pred -> 32 Spart, all in flight ----
    int ys[4];
    #pragma unroll
    for (int r = 0; r < 4; ++r) ys[r] = labels[r * 1024 + gw];
    float pv[4];
    #pragma unroll
    for (int r = 0; r < 4; ++r) pv[r] = pred[(size_t)(r * 1024 + gw) * C_CLS + lane];
    float sp[4];
    #pragma unroll
    for (int r = 0; r < 4; ++r) {
        float s = 0.0f;
        #pragma unroll
        for (int k = 0; k < KCHUNK; ++k)
            s += g_Spart[k * C_CLS * C_CLS + ys[r] * C_CLS + lane];
        sp[r] = s;
    }

    float acc_nll = 0.0f;
    #pragma unroll
    for (int r = 0; r < 4; ++r) {
        const float logit = pv[r] + lam * sp[r];
        float m = logit;
        #pragma unroll
        for (int off = 32; off > 0; off >>= 1)
            m = fmaxf(m, __shfl_xor(m, off, 64));
        float e = __expf(logit - m);
        float ssum = e;
        #pragma unroll
        for (int off = 32; off > 0; off >>= 1)
            ssum += __shfl_xor(ssum, off, 64);
        const float ly = __shfl(logit, ys[r], 64);
        acc_nll += logf(ssum) + m - ly;
    }

    if (lane == 0) wsum[wv] = acc_nll;
    __syncthreads();
    if (t == 0) {
        // sc1 store lands at the LLC (agent coherence point); vmcnt drain
        // orders it before my ticket RMW. No cache sweeps anywhere.
        __hip_atomic_store(&g_part[blockIdx.x],
                           wsum[0] + wsum[1] + wsum[2] + wsum[3],
                           __ATOMIC_RELAXED, __HIP_MEMORY_SCOPE_AGENT);
        asm volatile("s_waitcnt vmcnt(0)" ::: "memory");
        unsigned v = __hip_atomic_fetch_add(&g_tick, 1u, __ATOMIC_RELAXED,
                                            __HIP_MEMORY_SCOPE_AGENT) + 1u;
        s_last = ((v & (LOSS_BLOCKS - 1u)) == 0u) ? 1 : 0;
    }
    __syncthreads();

    // ---- last block: deterministic reduce of 256 partials -> mean loss ----
    if (s_last) {
        float v = __hip_atomic_load(&g_part[t], __ATOMIC_RELAXED,
                                    __HIP_MEMORY_SCOPE_AGENT);
        #pragma unroll
        for (int off = 32; off > 0; off >>= 1)
            v += __shfl_xor(v, off, 64);
        if (lane == 0) wsum[wv] = v;
        __syncthreads();
        if (t == 0)
            out[0] = (wsum[0] + wsum[1] + wsum[2] + wsum[3])
                     * (1.0f / (float)N_ROWS);
    }
}

// ---------------------------------------------------------------------------
extern "C" void kernel_launch(void* const* d_in, const int* in_sizes, int n_in,
                              void* d_out, int out_size, void* d_ws, size_t ws_size,
                              hipStream_t stream) {
    (void)in_sizes; (void)n_in; (void)out_size; (void)d_ws; (void)ws_size;
    const float* W      = (const float*)d_in[0];   // fc_weight [64][256]
    // d_in[1] = features (unused by the reference computation)
    const float* pred   = (const float*)d_in[2];   // [4096][64]
    const int*   labels = (const int*)d_in[3];     // [4096]
    const float* lam    = (const float*)d_in[4];   // scalar
    const float* CV     = (const float*)d_in[5];   // [64][256][256]
    float* out = (float*)d_out;

    qform_kernel<<<dim3(C_CLS * KCHUNK), dim3(256), 0, stream>>>(W, CV);
    loss_kernel<<<dim3(LOSS_BLOCKS), dim3(256), 0, stream>>>(pred, labels, lam, out);
}